// Round 12
// baseline (49.841 us; speedup 1.0000x reference)
//
#include <hip/hip_runtime.h>
#include <math.h>

#define BB 4096
#define MM 100
#define EE 128
#define RR 64

typedef float v4f __attribute__((ext_vector_type(4)));
typedef float v2f __attribute__((ext_vector_type(2)));

__device__ __forceinline__ v4f ld4v(const float* p) {
    return *reinterpret_cast<const v4f*>(p);
}
__device__ __forceinline__ void st4v(float* p, v4f v) {
    *reinterpret_cast<v4f*>(p) = v;
}
// 8-elem dot via packed fp32 (v_pk_fma_f32): 4 pk-ops + 1 scalar add
__device__ __forceinline__ float pdot8(v4f a, v4f qa, v4f b, v4f qb) {
    v2f acc = a.xy * qa.xy;
    acc += a.zw * qa.zw;
    acc += b.xy * qb.xy;
    acc += b.zw * qb.zw;
    return acc.x + acc.y;
}
__device__ __forceinline__ v4f v4red(v4f a, int off) {
    a.x += __shfl_xor(a.x, off, 64); a.y += __shfl_xor(a.y, off, 64);
    a.z += __shfl_xor(a.z, off, 64); a.w += __shfl_xor(a.w, off, 64);
    return a;
}
// rel = x1*w1*(S1*i1) + x2*w2*(S2*i2), elementwise (packed)
__device__ __forceinline__ v4f relcomb(v4f x1, v4f w1, v4f S1v, float i1,
                                       v4f x2, v4f w2, v4f S2v, float i2) {
    return x1 * w1 * (S1v * i1) + x2 * w2 * (S2v * i2);
}

// ---- DPP rotation all-reduce within a 16-lane row (pure VALU, no LDS pipe) ----
template<int CTRL>
__device__ __forceinline__ float dpp_add(float x) {
    int y = __builtin_amdgcn_update_dpp(0, __float_as_int(x), CTRL, 0xF, 0xF, true);
    return x + __int_as_float(y);
}
__device__ __forceinline__ float row16_allreduce(float x) {
    x = dpp_add<0x121>(x);   // row_ror:1
    x = dpp_add<0x122>(x);   // row_ror:2
    x = dpp_add<0x124>(x);   // row_ror:4
    x = dpp_add<0x128>(x);   // row_ror:8
    return x;
}

// ---- ws vectors: block 0 -> sum(ua_key*ua_val) over R; block 1 -> ia ----
__global__ __launch_bounds__(512)
void wsum_kernel(const float* __restrict__ ua_key, const float* __restrict__ ua_val,
                 const float* __restrict__ ia_key, const float* __restrict__ ia_val,
                 float* __restrict__ ws) {
    __shared__ float part[4][EE];
    const float* k = (blockIdx.x == 0) ? ua_key : ia_key;
    const float* v = (blockIdx.x == 0) ? ua_val : ia_val;
    int e = threadIdx.x & 127;
    int q = threadIdx.x >> 7;
    float s = 0.f;
    #pragma unroll
    for (int j = 0; j < 16; ++j) {
        int r = q * 16 + j;
        s += k[r * EE + e] * v[r * EE + e];
    }
    part[q][e] = s;
    __syncthreads();
    if (threadIdx.x < EE)
        ws[blockIdx.x * EE + e] = part[0][e] + part[1][e] + part[2][e] + part[3][e];
}

// One wave = one block = one b. 4 groups of 16 lanes; group g owns rows 4s+g,
// s = 0..24 (exactly 100 rows, no masking). Depth-8 register pipeline:
// 16 outstanding 16B/lane loads per wave -> latency cover ~8 steps.
// No min-waves clause: (64,4) capped VGPR=64 and spilled ~260 MB (R6).
__global__ __launch_bounds__(64)
void hlrm_main(const int* __restrict__ user_id,
               const int* __restrict__ ip_id,
               const int* __restrict__ in_id,
               const int* __restrict__ inter_id,
               const float* __restrict__ user_w,
               const float* __restrict__ item_w,
               const float* __restrict__ ws,
               float* __restrict__ out) {
    __shared__ int sw[MM];   // 400 B: this b's inter ids

    const int b    = blockIdx.x;
    const int lane = threadIdx.x;   // 0..63
    const int g    = lane >> 4;
    const int hl   = lane & 15;
    const int e0   = hl * 4;

    // ---- earliest: sids for steps 0..7 direct from global + stage all 100 ----
    const int* ib = inter_id + b * MM;
    int sid0 = ib[g],      sid1 = ib[4 + g],  sid2 = ib[8 + g],  sid3 = ib[12 + g];
    int sid4 = ib[16 + g], sid5 = ib[20 + g], sid6 = ib[24 + g], sid7 = ib[28 + g];
    if (lane < 50)
        *reinterpret_cast<int2*>(sw + 2 * lane) =
            *reinterpret_cast<const int2*>(ib + 2 * lane);

    // entity ids (uniform) + rows + ws
    int uid = user_id[b], pid = ip_id[b], nid = in_id[b];
    const float* pu = user_w + ((uint)uid << 7);
    const float* pp = item_w + ((uint)pid << 7);
    const float* pn = item_w + ((uint)nid << 7);
    v4f ru_a = ld4v(pu + e0), ru_b = ld4v(pu + e0 + 64);
    v4f rp_a = ld4v(pp + e0), rp_b = ld4v(pp + e0 + 64);
    v4f rn_a = ld4v(pn + e0), rn_b = ld4v(pn + e0 + 64);
    v4f waa = ld4v(ws + e0),       wab = ld4v(ws + e0 + 64);
    v4f wia = ld4v(ws + 128 + e0), wib = ld4v(ws + 192 + e0);

    // ---- issue tiles for steps 0..7 (depth-8 pipeline) ----
    v4f va0, vb0, va1, vb1, va2, vb2, va3, vb3;
    v4f va4, vb4, va5, vb5, va6, vb6, va7, vb7;
#define LOADT(J) do {                                             \
        const float* pt = item_w + ((uint)sid##J << 7) + e0;      \
        va##J = ld4v(pt);                                         \
        vb##J = ld4v(pt + 64);                                    \
    } while (0)
    LOADT(0); LOADT(1); LOADT(2); LOADT(3);
    LOADT(4); LOADT(5); LOADT(6); LOADT(7);

    // ---- norms/scales for u, ip, inn (redundant per 16-lane group) ----
    float ssu = pdot8(ru_a, ru_a, ru_b, ru_b);
    float ssp = pdot8(rp_a, rp_a, rp_b, rp_b);
    float ssn = pdot8(rn_a, rn_a, rn_b, rn_b);
    ssu = row16_allreduce(ssu);
    ssp = row16_allreduce(ssp);
    ssn = row16_allreduce(ssn);
    float scu = (ssu > 1.f) ? __builtin_amdgcn_rsqf(ssu) : 1.f;
    float scp = (ssp > 1.f) ? __builtin_amdgcn_rsqf(ssp) : 1.f;
    float scn = (ssn > 1.f) ? __builtin_amdgcn_rsqf(ssn) : 1.f;

    // ---- q fragments (4 queries x 8 elems per lane), packed math ----
    float cup = scu * scp, cun = scu * scn;
    v4f qa0 = ru_a * rp_a * waa * cup, qb0 = ru_b * rp_b * wab * cup;
    v4f qa1 = ru_a * rp_a * wia * cup, qb1 = ru_b * rp_b * wib * cup;
    v4f qa2 = ru_a * rn_a * waa * cun, qb2 = ru_b * rn_b * wab * cun;
    v4f qa3 = ru_a * rn_a * wia * cun, qb3 = ru_b * rn_b * wib * cun;

    v4f Sa0 = {0,0,0,0}, Sa1 = {0,0,0,0}, Sa2 = {0,0,0,0}, Sa3 = {0,0,0,0};
    v4f Sb0 = {0,0,0,0}, Sb1 = {0,0,0,0}, Sb2 = {0,0,0,0}, Sb3 = {0,0,0,0};
    float den0 = 0.f, den1 = 0.f, den2 = 0.f, den3 = 0.f;

    // sids for steps 8..15 (rows 32+4j+g) from LDS (same-wave DS ordering)
    sid0 = sw[32 + g]; sid1 = sw[36 + g]; sid2 = sw[40 + g]; sid3 = sw[44 + g];
    sid4 = sw[48 + g]; sid5 = sw[52 + g]; sid6 = sw[56 + g]; sid7 = sw[60 + g];

#define STEP(J) do {                                                        \
        float ss = pdot8(va##J, va##J, vb##J, vb##J);                       \
        float d0 = pdot8(va##J, qa0, vb##J, qb0);                           \
        float d1 = pdot8(va##J, qa1, vb##J, qb1);                           \
        float d2 = pdot8(va##J, qa2, vb##J, qb2);                           \
        float d3 = pdot8(va##J, qa3, vb##J, qb3);                           \
        ss = row16_allreduce(ss);                                           \
        d0 = row16_allreduce(d0); d1 = row16_allreduce(d1);                 \
        d2 = row16_allreduce(d2); d3 = row16_allreduce(d3);                 \
        float sc = (ss > 1.f) ? __builtin_amdgcn_rsqf(ss) : 1.f;            \
        float w0 = __expf(d0 * sc), w1 = __expf(d1 * sc);                   \
        float w2 = __expf(d2 * sc), w3 = __expf(d3 * sc);                   \
        den0 += w0; den1 += w1; den2 += w2; den3 += w3;                     \
        w0 *= sc; w1 *= sc; w2 *= sc; w3 *= sc;                             \
        Sa0 += va##J * w0; Sb0 += vb##J * w0;                               \
        Sa1 += va##J * w1; Sb1 += vb##J * w1;                               \
        Sa2 += va##J * w2; Sb2 += vb##J * w2;                               \
        Sa3 += va##J * w3; Sb3 += vb##J * w3;                               \
    } while (0)

    // ---- 25 steps: 2 bodies of 8 (loads for s+8), steps 16..23 (+step-24 load), step 24
    #pragma unroll 1
    for (int it = 0; it < 2; ++it) {
        STEP(0); LOADT(0);
        STEP(1); LOADT(1);
        STEP(2); LOADT(2);
        STEP(3); LOADT(3);
        STEP(4); LOADT(4);
        STEP(5); LOADT(5);
        STEP(6); LOADT(6);
        STEP(7); LOADT(7);
        if (it == 0) {   // sids for steps 16..23 (rows 64+4j+g)
            sid0 = sw[64 + g]; sid1 = sw[68 + g]; sid2 = sw[72 + g]; sid3 = sw[76 + g];
            sid4 = sw[80 + g]; sid5 = sw[84 + g]; sid6 = sw[88 + g]; sid7 = sw[92 + g];
        } else {         // sid for step 24 (row 96+g)
            sid0 = sw[96 + g];
        }
    }
    STEP(0); LOADT(0);                    // step 16; buf0 <- step-24 tile
    STEP(1); STEP(2); STEP(3); STEP(4);   // steps 17..20
    STEP(5); STEP(6); STEP(7);            // steps 21..23
    STEP(0);                              // step 24
#undef STEP
#undef LOADT

    // ---- cross-group combine (off 16, 32): disjoint row sets, same e-slice ----
    #pragma unroll
    for (int off = 16; off < 64; off <<= 1) {
        Sa0 = v4red(Sa0, off); Sb0 = v4red(Sb0, off);
        Sa1 = v4red(Sa1, off); Sb1 = v4red(Sb1, off);
        Sa2 = v4red(Sa2, off); Sb2 = v4red(Sb2, off);
        Sa3 = v4red(Sa3, off); Sb3 = v4red(Sb3, off);
        den0 += __shfl_xor(den0, off, 64);
        den1 += __shfl_xor(den1, off, 64);
        den2 += __shfl_xor(den2, off, 64);
        den3 += __shfl_xor(den3, off, 64);
    }
    float iD0 = 1.f / den0, iD1 = 1.f / den1, iD2 = 1.f / den2, iD3 = 1.f / den3;

    // ---- epilogue: reload entity rows (cache-hot), scale, emit all 5 outputs ----
    const float* qu = user_w + ((uint)uid << 7);
    const float* qp = item_w + ((uint)pid << 7);
    const float* qn = item_w + ((uint)nid << 7);
    v4f u_a = ld4v(qu + e0) * scu,      u_b = ld4v(qu + e0 + 64) * scu;
    v4f p_a = ld4v(qp + e0) * scp,      p_b = ld4v(qp + e0 + 64) * scp;
    v4f n_a = ld4v(qn + e0) * scn,      n_b = ld4v(qn + e0 + 64) * scn;
    v4f w0a = ld4v(ws + e0),            w0b = ld4v(ws + e0 + 64);
    v4f w1a = ld4v(ws + 128 + e0),      w1b = ld4v(ws + 192 + e0);

    size_t base = (size_t)b * EE;
    const size_t P = (size_t)BB * EE;
    if (g == 0) {
        v4f ra = relcomb(p_a, w0a, Sa0, iD0, u_a, w1a, Sa1, iD1);
        v4f rb = relcomb(p_b, w0b, Sb0, iD0, u_b, w1b, Sb1, iD1);
        st4v(out + 3 * P + base + e0, ra);
        st4v(out + 3 * P + base + e0 + 64, rb);
    } else if (g == 1) {
        v4f ra = relcomb(n_a, w0a, Sa2, iD2, u_a, w1a, Sa3, iD3);
        v4f rb = relcomb(n_b, w0b, Sb2, iD2, u_b, w1b, Sb3, iD3);
        st4v(out + 4 * P + base + e0, ra);
        st4v(out + 4 * P + base + e0 + 64, rb);
    } else if (g == 2) {
        st4v(out + 0 * P + base + e0, u_a);
        st4v(out + 0 * P + base + e0 + 64, u_b);
        st4v(out + 1 * P + base + e0, p_a);
        st4v(out + 1 * P + base + e0 + 64, p_b);
    } else {
        st4v(out + 2 * P + base + e0, n_a);
        st4v(out + 2 * P + base + e0 + 64, n_b);
    }
}

extern "C" void kernel_launch(void* const* d_in, const int* in_sizes, int n_in,
                              void* d_out, int out_size, void* d_ws, size_t ws_size,
                              hipStream_t stream) {
    const int*   user_id   = (const int*)d_in[0];
    const int*   item_id_p = (const int*)d_in[1];
    const int*   item_id_n = (const int*)d_in[2];
    const int*   inter_id  = (const int*)d_in[3];
    const float* user_w    = (const float*)d_in[4];
    const float* item_w    = (const float*)d_in[5];
    const float* ua_key    = (const float*)d_in[6];
    const float* ua_val    = (const float*)d_in[7];
    const float* ia_key    = (const float*)d_in[8];
    const float* ia_val    = (const float*)d_in[9];
    float* out = (float*)d_out;
    float* ws  = (float*)d_ws;   // [0:128)=wsum_ua, [128:256)=wsum_ia

    wsum_kernel<<<2, 512, 0, stream>>>(ua_key, ua_val, ia_key, ia_val, ws);
    hlrm_main<<<BB, 64, 0, stream>>>(user_id, item_id_p, item_id_n, inter_id,
                                     user_w, item_w, ws, out);
}

// Round 13
// 42.904 us; speedup vs baseline: 1.1617x; 1.1617x over previous
//
#include <hip/hip_runtime.h>
#include <math.h>

#define BB 4096
#define MM 100
#define EE 128
#define RR 64

typedef float v4f __attribute__((ext_vector_type(4)));
typedef float v2f __attribute__((ext_vector_type(2)));

__device__ __forceinline__ v4f ld4v(const float* p) {
    return *reinterpret_cast<const v4f*>(p);
}
__device__ __forceinline__ void st4v(float* p, v4f v) {
    *reinterpret_cast<v4f*>(p) = v;
}
// 8-elem dot via packed fp32 (v_pk_fma_f32): 4 pk-ops + 1 scalar add
__device__ __forceinline__ float pdot8(v4f a, v4f qa, v4f b, v4f qb) {
    v2f acc = a.xy * qa.xy;
    acc += a.zw * qa.zw;
    acc += b.xy * qb.xy;
    acc += b.zw * qb.zw;
    return acc.x + acc.y;
}
__device__ __forceinline__ v4f v4red(v4f a, int off) {
    a.x += __shfl_xor(a.x, off, 64); a.y += __shfl_xor(a.y, off, 64);
    a.z += __shfl_xor(a.z, off, 64); a.w += __shfl_xor(a.w, off, 64);
    return a;
}
// rel = x1*w1*(S1*i1) + x2*w2*(S2*i2), elementwise (packed)
__device__ __forceinline__ v4f relcomb(v4f x1, v4f w1, v4f S1v, float i1,
                                       v4f x2, v4f w2, v4f S2v, float i2) {
    return x1 * w1 * (S1v * i1) + x2 * w2 * (S2v * i2);
}

// ---- DPP rotation all-reduce within a 16-lane row (pure VALU, no LDS pipe) ----
template<int CTRL>
__device__ __forceinline__ float dpp_add(float x) {
    int y = __builtin_amdgcn_update_dpp(0, __float_as_int(x), CTRL, 0xF, 0xF, true);
    return x + __int_as_float(y);
}
__device__ __forceinline__ float row16_allreduce(float x) {
    x = dpp_add<0x121>(x);   // row_ror:1
    x = dpp_add<0x122>(x);   // row_ror:2
    x = dpp_add<0x124>(x);   // row_ror:4
    x = dpp_add<0x128>(x);   // row_ror:8
    return x;
}

// ---- ws vectors: block 0 -> sum(ua_key*ua_val) over R; block 1 -> ia ----
__global__ __launch_bounds__(512)
void wsum_kernel(const float* __restrict__ ua_key, const float* __restrict__ ua_val,
                 const float* __restrict__ ia_key, const float* __restrict__ ia_val,
                 float* __restrict__ ws) {
    __shared__ float part[4][EE];
    const float* k = (blockIdx.x == 0) ? ua_key : ia_key;
    const float* v = (blockIdx.x == 0) ? ua_val : ia_val;
    int e = threadIdx.x & 127;
    int q = threadIdx.x >> 7;
    float s = 0.f;
    #pragma unroll
    for (int j = 0; j < 16; ++j) {
        int r = q * 16 + j;
        s += k[r * EE + e] * v[r * EE + e];
    }
    part[q][e] = s;
    __syncthreads();
    if (threadIdx.x < EE)
        ws[blockIdx.x * EE + e] = part[0][e] + part[1][e] + part[2][e] + part[3][e];
}

// One wave = one block = one b. 4 groups of 16 lanes; group g owns rows 4s+g,
// s = 0..24 (exactly 100 rows). Depth-5 register pipeline: 10 outstanding
// 16B/lane loads -> 5-step latency cover at VGPR <= 128 (4 waves/SIMD bin).
// R12 lesson: depth-8 -> VGPR 168 -> 2 waves/SIMD bin -> regression.
__global__ __launch_bounds__(64)
void hlrm_main(const int* __restrict__ user_id,
               const int* __restrict__ ip_id,
               const int* __restrict__ in_id,
               const int* __restrict__ inter_id,
               const float* __restrict__ user_w,
               const float* __restrict__ item_w,
               const float* __restrict__ ws,
               float* __restrict__ out) {
    __shared__ int sw[MM];   // 400 B: this b's inter ids

    const int b    = blockIdx.x;
    const int lane = threadIdx.x;   // 0..63
    const int g    = lane >> 4;
    const int hl   = lane & 15;
    const int e0   = hl * 4;

    // ---- earliest: sids for steps 0..4 direct from global, issue tiles ----
    const int* ib = inter_id + b * MM;
    int sid0 = ib[g],      sid1 = ib[4 + g],  sid2 = ib[8 + g],
        sid3 = ib[12 + g], sid4 = ib[16 + g];

    v4f va0, vb0, va1, vb1, va2, vb2, va3, vb3, va4, vb4;
#define LOADT(J) do {                                             \
        const float* pt = item_w + ((uint)sid##J << 7) + e0;      \
        va##J = ld4v(pt);                                         \
        vb##J = ld4v(pt + 64);                                    \
    } while (0)
    LOADT(0); LOADT(1); LOADT(2); LOADT(3); LOADT(4);

    // stage all 100 ids to LDS (single wave -> same-wave DS ordering, no barrier)
    if (lane < 50)
        *reinterpret_cast<int2*>(sw + 2 * lane) =
            *reinterpret_cast<const int2*>(ib + 2 * lane);

    // entity ids (uniform) + rows + ws
    int uid = user_id[b], pid = ip_id[b], nid = in_id[b];
    const float* pu = user_w + ((uint)uid << 7);
    const float* pp = item_w + ((uint)pid << 7);
    const float* pn = item_w + ((uint)nid << 7);
    v4f ru_a = ld4v(pu + e0), ru_b = ld4v(pu + e0 + 64);
    v4f rp_a = ld4v(pp + e0), rp_b = ld4v(pp + e0 + 64);
    v4f rn_a = ld4v(pn + e0), rn_b = ld4v(pn + e0 + 64);
    v4f waa = ld4v(ws + e0),       wab = ld4v(ws + e0 + 64);
    v4f wia = ld4v(ws + 128 + e0), wib = ld4v(ws + 192 + e0);

    // ---- norms/scales for u, ip, inn (redundant per 16-lane group) ----
    float ssu = pdot8(ru_a, ru_a, ru_b, ru_b);
    float ssp = pdot8(rp_a, rp_a, rp_b, rp_b);
    float ssn = pdot8(rn_a, rn_a, rn_b, rn_b);
    ssu = row16_allreduce(ssu);
    ssp = row16_allreduce(ssp);
    ssn = row16_allreduce(ssn);
    float scu = (ssu > 1.f) ? __builtin_amdgcn_rsqf(ssu) : 1.f;
    float scp = (ssp > 1.f) ? __builtin_amdgcn_rsqf(ssp) : 1.f;
    float scn = (ssn > 1.f) ? __builtin_amdgcn_rsqf(ssn) : 1.f;

    // ---- q fragments (4 queries x 8 elems per lane), packed math ----
    float cup = scu * scp, cun = scu * scn;
    v4f qa0 = ru_a * rp_a * waa * cup, qb0 = ru_b * rp_b * wab * cup;
    v4f qa1 = ru_a * rp_a * wia * cup, qb1 = ru_b * rp_b * wib * cup;
    v4f qa2 = ru_a * rn_a * waa * cun, qb2 = ru_b * rn_b * wab * cun;
    v4f qa3 = ru_a * rn_a * wia * cun, qb3 = ru_b * rn_b * wib * cun;

    v4f Sa0 = {0,0,0,0}, Sa1 = {0,0,0,0}, Sa2 = {0,0,0,0}, Sa3 = {0,0,0,0};
    v4f Sb0 = {0,0,0,0}, Sb1 = {0,0,0,0}, Sb2 = {0,0,0,0}, Sb3 = {0,0,0,0};
    float den0 = 0.f, den1 = 0.f, den2 = 0.f, den3 = 0.f;

    // sids for steps 5..9 (rows 20+4j+g) from LDS
    sid0 = sw[20 + g]; sid1 = sw[24 + g]; sid2 = sw[28 + g];
    sid3 = sw[32 + g]; sid4 = sw[36 + g];

#define STEP(J) do {                                                        \
        float ss = pdot8(va##J, va##J, vb##J, vb##J);                       \
        float d0 = pdot8(va##J, qa0, vb##J, qb0);                           \
        float d1 = pdot8(va##J, qa1, vb##J, qb1);                           \
        float d2 = pdot8(va##J, qa2, vb##J, qb2);                           \
        float d3 = pdot8(va##J, qa3, vb##J, qb3);                           \
        ss = row16_allreduce(ss);                                           \
        d0 = row16_allreduce(d0); d1 = row16_allreduce(d1);                 \
        d2 = row16_allreduce(d2); d3 = row16_allreduce(d3);                 \
        float sc = (ss > 1.f) ? __builtin_amdgcn_rsqf(ss) : 1.f;            \
        float w0 = __expf(d0 * sc), w1 = __expf(d1 * sc);                   \
        float w2 = __expf(d2 * sc), w3 = __expf(d3 * sc);                   \
        den0 += w0; den1 += w1; den2 += w2; den3 += w3;                     \
        w0 *= sc; w1 *= sc; w2 *= sc; w3 *= sc;                             \
        Sa0 += va##J * w0; Sb0 += vb##J * w0;                               \
        Sa1 += va##J * w1; Sb1 += vb##J * w1;                               \
        Sa2 += va##J * w2; Sb2 += vb##J * w2;                               \
        Sa3 += va##J * w3; Sb3 += vb##J * w3;                               \
    } while (0)

    // ---- 25 steps: 4 bodies of 5 (loads for s+5) + 5-step tail ----
    #pragma unroll 1
    for (int it = 0; it < 4; ++it) {
        STEP(0); LOADT(0);
        STEP(1); LOADT(1);
        STEP(2); LOADT(2);
        STEP(3); LOADT(3);
        STEP(4); LOADT(4);
        if (it < 3) {   // sids for steps 5(it+2)+j, j=0..4
            int o = 20 * it + 40 + g;
            sid0 = sw[o];      sid1 = sw[o + 4];  sid2 = sw[o + 8];
            sid3 = sw[o + 12]; sid4 = sw[o + 16];
        }
    }
    STEP(0); STEP(1); STEP(2); STEP(3); STEP(4);   // steps 20..24
#undef STEP
#undef LOADT

    // ---- cross-group combine (off 16, 32): disjoint row sets, same e-slice ----
    #pragma unroll
    for (int off = 16; off < 64; off <<= 1) {
        Sa0 = v4red(Sa0, off); Sb0 = v4red(Sb0, off);
        Sa1 = v4red(Sa1, off); Sb1 = v4red(Sb1, off);
        Sa2 = v4red(Sa2, off); Sb2 = v4red(Sb2, off);
        Sa3 = v4red(Sa3, off); Sb3 = v4red(Sb3, off);
        den0 += __shfl_xor(den0, off, 64);
        den1 += __shfl_xor(den1, off, 64);
        den2 += __shfl_xor(den2, off, 64);
        den3 += __shfl_xor(den3, off, 64);
    }
    float iD0 = 1.f / den0, iD1 = 1.f / den1, iD2 = 1.f / den2, iD3 = 1.f / den3;

    // ---- epilogue: reload entity rows (cache-hot), scale, emit all 5 outputs ----
    const float* qu = user_w + ((uint)uid << 7);
    const float* qp = item_w + ((uint)pid << 7);
    const float* qn = item_w + ((uint)nid << 7);
    v4f u_a = ld4v(qu + e0) * scu,      u_b = ld4v(qu + e0 + 64) * scu;
    v4f p_a = ld4v(qp + e0) * scp,      p_b = ld4v(qp + e0 + 64) * scp;
    v4f n_a = ld4v(qn + e0) * scn,      n_b = ld4v(qn + e0 + 64) * scn;
    v4f w0a = ld4v(ws + e0),            w0b = ld4v(ws + e0 + 64);
    v4f w1a = ld4v(ws + 128 + e0),      w1b = ld4v(ws + 192 + e0);

    size_t base = (size_t)b * EE;
    const size_t P = (size_t)BB * EE;
    if (g == 0) {
        v4f ra = relcomb(p_a, w0a, Sa0, iD0, u_a, w1a, Sa1, iD1);
        v4f rb = relcomb(p_b, w0b, Sb0, iD0, u_b, w1b, Sb1, iD1);
        st4v(out + 3 * P + base + e0, ra);
        st4v(out + 3 * P + base + e0 + 64, rb);
    } else if (g == 1) {
        v4f ra = relcomb(n_a, w0a, Sa2, iD2, u_a, w1a, Sa3, iD3);
        v4f rb = relcomb(n_b, w0b, Sb2, iD2, u_b, w1b, Sb3, iD3);
        st4v(out + 4 * P + base + e0, ra);
        st4v(out + 4 * P + base + e0 + 64, rb);
    } else if (g == 2) {
        st4v(out + 0 * P + base + e0, u_a);
        st4v(out + 0 * P + base + e0 + 64, u_b);
        st4v(out + 1 * P + base + e0, p_a);
        st4v(out + 1 * P + base + e0 + 64, p_b);
    } else {
        st4v(out + 2 * P + base + e0, n_a);
        st4v(out + 2 * P + base + e0 + 64, n_b);
    }
}

extern "C" void kernel_launch(void* const* d_in, const int* in_sizes, int n_in,
                              void* d_out, int out_size, void* d_ws, size_t ws_size,
                              hipStream_t stream) {
    const int*   user_id   = (const int*)d_in[0];
    const int*   item_id_p = (const int*)d_in[1];
    const int*   item_id_n = (const int*)d_in[2];
    const int*   inter_id  = (const int*)d_in[3];
    const float* user_w    = (const float*)d_in[4];
    const float* item_w    = (const float*)d_in[5];
    const float* ua_key    = (const float*)d_in[6];
    const float* ua_val    = (const float*)d_in[7];
    const float* ia_key    = (const float*)d_in[8];
    const float* ia_val    = (const float*)d_in[9];
    float* out = (float*)d_out;
    float* ws  = (float*)d_ws;   // [0:128)=wsum_ua, [128:256)=wsum_ia

    wsum_kernel<<<2, 512, 0, stream>>>(ua_key, ua_val, ia_key, ia_val, ws);
    hlrm_main<<<BB, 64, 0, stream>>>(user_id, item_id_p, item_id_n, inter_id,
                                     user_w, item_w, ws, out);
}